// Round 7
// baseline (175.624 us; speedup 1.0000x reference)
//
#include <hip/hip_runtime.h>
#include <stdint.h>

#define BATCH 16
#define NPTS 500000
#define QPTS (NPTS / 4)        // 125000 quads
#define DBITS 21
#define DSIZE (1u << DBITS)
#define VOFF 969696            // di = vid + VOFF in [0, 2^21)
#define HBINS 256
#define CAP 8192
#define KTOP 512
#define NBKT 64
#define CPB 32768              // cells per bucket
#define CAPL 16384             // uint16 list capacity per bucket (2.1x mean 7812)
#define SCT 1024               // scatter block threads
#define SCQ 2048               // quads per scatter block (8 points/thread)
#define SCB ((QPTS + SCQ - 1) / SCQ)   // 62 blocks per batch
#define CHQ ((QPTS + 255) / 256)       // 489 label chunks per batch
#define CCAP 262144            // compact entries capacity per batch (~100k used)
#define WBITS 11
#define WSIZE (1 << WBITS)
#define WMASK (WSIZE - 1)
#define WEMPTY 0xFFFFFFFFu

// meta layout per batch (8 ints)
#define M_MODE 0
#define M_T 1
#define M_ORIGIN 2

typedef float fvec4 __attribute__((ext_vector_type(4)));
typedef int ivec4 __attribute__((ext_vector_type(4)));

// Must match JAX/np exactly: IEEE f32 divide (NOT *5.0f), trunc-toward-zero cast.
__device__ __forceinline__ uint32_t didx_of(float x, float y, float z) {
    int vx = (int)(x / 0.2f);
    int vy = (int)(y / 0.2f);
    int vz = (int)(z / 0.2f);
    int di = vx * 10000 + vy * 100 + vz + VOFF;
    di = di < 0 ? 0 : di;
    di = di > (int)DSIZE - 1 ? (int)DSIZE - 1 : di;  // unreachable (9.6 sigma); safety only
    return (uint32_t)di;
}

__device__ __forceinline__ void didx4_of(const float* base, int q, uint32_t di[4]) {
    const fvec4* cp = (const fvec4*)(base) + (size_t)q * 3;
    fvec4 f0 = __builtin_nontemporal_load(cp);
    fvec4 f1 = __builtin_nontemporal_load(cp + 1);
    fvec4 f2 = __builtin_nontemporal_load(cp + 2);
    di[0] = didx_of(f0.x, f0.y, f0.z);
    di[1] = didx_of(f0.w, f1.x, f1.y);
    di[2] = didx_of(f1.z, f1.w, f2.x);
    di[3] = didx_of(f2.y, f2.z, f2.w);
}

__device__ __forceinline__ uint32_t bkt_of(uint32_t d) {
    return ((d >> 15) ^ (d >> 9)) & 63u;   // A ^ B: decorrelates Gaussian vx alignment
}

// Radix partition + per-point di store. Global atomics: 64 cursor ops per block.
__global__ void __launch_bounds__(SCT) scatter_kernel(const float* __restrict__ coords,
                                                      uint16_t* __restrict__ lists,
                                                      uint32_t* __restrict__ dis,
                                                      int* __restrict__ cursor,
                                                      int* __restrict__ meta) {
    int id = blockIdx.x;
    int b = id & 15;
    int chunk = id >> 4;
    int t = threadIdx.x;
    __shared__ int bcount[NBKT], gbase[NBKT], brun[NBKT];
    if (t < NBKT) { bcount[t] = 0; brun[t] = 0; }
    __syncthreads();
    int q0 = chunk * SCQ + t;
    int q1 = q0 + SCT;
    const float* cb = coords + (size_t)b * NPTS * 3;
    uint32_t di[2][4];
#pragma unroll
    for (int p = 0; p < 2; ++p) {
        int q = p ? q1 : q0;
        if (q < QPTS) {
            didx4_of(cb, q, di[p]);
            uint4 d4 = make_uint4(di[p][0], di[p][1], di[p][2], di[p][3]);
            ((uint4*)dis)[(size_t)b * QPTS + q] = d4;
#pragma unroll
            for (int u = 0; u < 4; ++u) {
                uint32_t d = di[p][u];
                if (d == (uint32_t)VOFF)
                    atomicAdd(&meta[b * 8 + M_ORIGIN], 1);  // rare (~254/batch)
                else
                    atomicAdd(&bcount[bkt_of(d)], 1);
            }
        }
    }
    __syncthreads();
    if (t < NBKT) gbase[t] = atomicAdd(&cursor[b * NBKT + t], bcount[t]);
    __syncthreads();
    uint16_t* lb = lists + (size_t)b * NBKT * CAPL;
#pragma unroll
    for (int p = 0; p < 2; ++p) {
        int q = p ? q1 : q0;
        if (q < QPTS) {
#pragma unroll
            for (int u = 0; u < 4; ++u) {
                uint32_t d = di[p][u];
                if (d == (uint32_t)VOFF) continue;
                uint32_t bk = bkt_of(d);
                int slot = atomicAdd(&brun[bk], 1);
                int idx = gbase[bk] + slot;
                if (idx < CAPL)
                    lb[bk * CAPL + idx] = (uint16_t)(((d >> 15) << 9) | (d & 511u));
            }
        }
    }
}

// One block per (batch,bucket): LDS byte counts -> histogram + COMPACT nonzero cells
// as packed entries ((255-count)<<21 | di). No dense grid ever hits global memory.
__global__ void __launch_bounds__(256) count_kernel(const uint16_t* __restrict__ lists,
                                                    const int* __restrict__ cursor,
                                                    int* __restrict__ hist,
                                                    uint32_t* __restrict__ compact,
                                                    int* __restrict__ ccur) {
    __shared__ unsigned int cnt[CPB / 4];  // 32 KB
    __shared__ int lhist[HBINS];
    __shared__ int ltot, lrun, gbase;
    int id = blockIdx.x;
    int b = id & 15;
    uint32_t bkt = (uint32_t)(id >> 4);
    int t = threadIdx.x;
    for (int i = t; i < CPB / 4; i += 256) cnt[i] = 0;
    lhist[t] = 0;
    if (t == 0) { ltot = 0; lrun = 0; }
    __syncthreads();
    const uint16_t* list = lists + ((size_t)b * NBKT + bkt) * CAPL;
    int n = cursor[b * NBKT + bkt];
    if (n > CAPL) n = CAPL;
    for (int i = t; i < n; i += 256) {
        uint32_t e = list[i];  // (A<<9)|C
        atomicAdd(&cnt[e >> 2], 1u << ((e & 3u) * 8u));  // fire-and-forget LDS atomic
    }
    __syncthreads();
    // pass A: histogram + count my nonzero cells
    int mycnt = 0;
    for (int i = t; i < CPB / 4; i += 256) {
        unsigned int w = cnt[i];
        if (!w) continue;
#pragma unroll
        for (int j = 0; j < 4; ++j) {
            unsigned int c = (w >> (j * 8)) & 0xFFu;
            if (c) { atomicAdd(&lhist[c], 1); ++mycnt; }
        }
    }
    if (mycnt) atomicAdd(&ltot, mycnt);
    __syncthreads();
    if (t == 0) gbase = atomicAdd(&ccur[b], ltot);
    if (lhist[t]) atomicAdd(&hist[b * HBINS + t], lhist[t]);
    __syncthreads();
    // pass B: emit packed entries into reserved range
    uint32_t* cmp = compact + (size_t)b * CCAP;
    for (int i = t; i < CPB / 4; i += 256) {
        unsigned int w = cnt[i];
        if (!w) continue;
#pragma unroll
        for (int j = 0; j < 4; ++j) {
            unsigned int c = (w >> (j * 8)) & 0xFFu;
            if (c) {
                uint32_t local = (uint32_t)i * 4u + (uint32_t)j;
                uint32_t A = local >> 9, C = local & 511u, B = bkt ^ A;
                uint32_t di = (A << 15) | (B << 9) | C;
                int slot = atomicAdd(&lrun, 1);
                int idx = gbase + slot;
                if (idx < CCAP) cmp[idx] = ((255u - c) << DBITS) | di;
            }
        }
    }
}

// Fused: append origin entry to compact list + suffix-scan histogram -> mode, T.
__global__ void fixthresh_kernel(int* __restrict__ meta, const int* __restrict__ hist,
                                 uint32_t* __restrict__ compact, int* __restrict__ ccur) {
    __shared__ int ls[HBINS];
    int b = blockIdx.x;
    int t = threadIdx.x;
    int oc = meta[b * 8 + M_ORIGIN];
    int ocl = oc > 255 ? 255 : oc;  // origin is the unique top cell (~254 vs ~35); rank-safe
    int h = (t >= 1) ? hist[b * HBINS + t] : 0;
    if (oc > 0 && t == ocl) h += 1;
    ls[t] = h;
    __syncthreads();
    for (int off = 1; off < HBINS; off <<= 1) {
        int v = (t + off < HBINS) ? ls[t + off] : 0;
        __syncthreads();
        ls[t] += v;
        __syncthreads();
    }
    int U = ls[1];
    if (t >= 1 && ls[t] >= KTOP && (t == HBINS - 1 || ls[t + 1] < KTOP))
        meta[b * 8 + M_T] = t;  // unique such t; no thread fires if U < KTOP
    if (t == 0) {
        meta[b * 8 + M_MODE] = (U > KTOP) ? 1 : 0;
        if (U <= KTOP) meta[b * 8 + M_T] = 1;
        if (oc > 0) {  // single writer now; plain RMW of ccur is safe
            int idx = ccur[b];
            if (idx < CCAP)
                compact[(size_t)b * CCAP + idx] = ((255u - (uint32_t)ocl) << DBITS) | VOFF;
            ccur[b] = idx + 1;
        }
    }
}

// Fused: filter compact by T -> LDS bitonic sort -> insert winner hash entries.
__global__ void __launch_bounds__(1024) sortrank_kernel(const uint32_t* __restrict__ compact,
                                                        const int* __restrict__ ccur,
                                                        const int* __restrict__ meta,
                                                        unsigned int* __restrict__ winners) {
    __shared__ uint32_t s[CAP];  // 32 KB
    __shared__ int scnt;
    int b = blockIdx.x;
    int t = threadIdx.x;
    int mode = meta[b * 8 + M_MODE];
    uint32_t T = (uint32_t)meta[b * 8 + M_T];
    if (T < 1) T = 1;
    uint32_t maxtop = 255u - T;  // keep entries with (e>>DBITS) <= 255-T  (count >= T)
    int n = ccur[b];
    if (n > CCAP) n = CCAP;
    if (t == 0) scnt = 0;
    __syncthreads();
    const uint32_t* cmp = compact + (size_t)b * CCAP;
    for (int i = t; i < n; i += 1024) {
        uint32_t e = cmp[i];
        if (mode ? ((e >> DBITS) <= maxtop) : true) {
            uint32_t key = mode ? e : (e & (DSIZE - 1u));  // mode0: rank by di only
            int idx = atomicAdd(&scnt, 1);
            if (idx < CAP) s[idx] = key;
        }
    }
    __syncthreads();
    int nk = scnt < CAP ? scnt : CAP;
    int P = 2;
    while (P < nk) P <<= 1;
    for (int i = nk + t; i < P; i += 1024) s[i] = 0xFFFFFFFFu;  // keys < 2^30
    __syncthreads();
    for (int k = 2; k <= P; k <<= 1) {
        for (int j = k >> 1; j > 0; j >>= 1) {
            for (int i = t; i < P; i += 1024) {
                int l = i ^ j;
                if (l > i) {
                    uint32_t a = s[i], c = s[l];
                    bool asc = ((i & k) == 0);
                    if ((asc && a > c) || (!asc && a < c)) { s[i] = c; s[l] = a; }
                }
            }
            __syncthreads();
        }
    }
    int nsel = mode ? (nk < KTOP ? nk : KTOP) : nk;  // mode0: nk = U <= 512
    unsigned int* wb = winners + (size_t)b * WSIZE;
    for (int j = t; j < nsel; j += 1024) {
        uint32_t di = s[j] & (DSIZE - 1u);
        uint32_t ins = (di << 9) | (uint32_t)j;  // 30 bits, != WEMPTY
        uint32_t h = (di * 0x9E3779B1u) >> (32 - WBITS);
        while (atomicCAS(&wb[h], WEMPTY, ins) != WEMPTY) h = (h + 1) & WMASK;
    }
}

// Read stored di per point; probe the 8 KB L1-resident winner hash; -1 on first empty.
__global__ void label_kernel(const uint32_t* __restrict__ dis,
                             const unsigned int* __restrict__ winners,
                             int* __restrict__ out) {
    int id = blockIdx.x;
    int b = id & 15;
    int q = (id >> 4) * 256 + threadIdx.x;
    if (q >= QPTS) return;
    uint4 d4 = ((const uint4*)dis)[(size_t)b * QPTS + q];
    uint32_t di[4] = {d4.x, d4.y, d4.z, d4.w};
    const unsigned int* wb = winners + (size_t)b * WSIZE;
    int r[4];
#pragma unroll
    for (int u = 0; u < 4; ++u) {
        uint32_t h = (di[u] * 0x9E3779B1u) >> (32 - WBITS);
        int rr = -1;
        while (true) {
            unsigned int w = wb[h];
            if (w == WEMPTY) break;
            if ((w >> 9) == di[u]) { rr = (int)(w & 0x1FFu); break; }
            h = (h + 1) & WMASK;
        }
        r[u] = rr;
    }
    ivec4 r4 = {r[0], r[1], r[2], r[3]};
    __builtin_nontemporal_store(r4, (ivec4*)(out + (size_t)b * NPTS + (size_t)q * 4));
}

extern "C" void kernel_launch(void* const* d_in, const int* in_sizes, int n_in,
                              void* d_out, int out_size, void* d_ws, size_t ws_size,
                              hipStream_t stream) {
    const float* coords = (const float*)d_in[0];
    int* out = (int*)d_out;
    char* ws = (char*)d_ws;

    size_t off = 0;
    uint16_t* lists = (uint16_t*)(ws + off);           off += (size_t)BATCH * NBKT * CAPL * 2;  // 32 MB
    uint32_t* dis = (uint32_t*)(ws + off);             off += (size_t)BATCH * NPTS * 4;         // 32 MB
    uint32_t* compact = (uint32_t*)(ws + off);         off += (size_t)BATCH * CCAP * 4;         // 16 MB
    int* cursor = (int*)(ws + off);                    off += (size_t)BATCH * NBKT * 4;         // 4 KB
    int* ccur = (int*)(ws + off);                      off += (size_t)BATCH * 4;                // 64 B
    int* hist = (int*)(ws + off);                      off += (size_t)BATCH * HBINS * 4;        // 16 KB
    int* meta = (int*)(ws + off);                      off += (size_t)BATCH * 8 * 4;            // 512 B
    unsigned int* winners = (unsigned int*)(ws + off); off += (size_t)BATCH * WSIZE * 4;        // 128 KB

    // Re-initialize every launch (harness does not re-poison between replays).
    // cursor+ccur+hist+meta contiguous: one memset. lists/dis/compact fully rewritten.
    hipMemsetAsync(cursor, 0,
                   (size_t)BATCH * NBKT * 4 + (size_t)BATCH * 4 +
                   (size_t)BATCH * HBINS * 4 + (size_t)BATCH * 8 * 4, stream);
    hipMemsetAsync(winners, 0xFF, (size_t)BATCH * WSIZE * 4, stream);

    scatter_kernel<<<SCB * BATCH, SCT, 0, stream>>>(coords, lists, dis, cursor, meta);
    count_kernel<<<NBKT * BATCH, 256, 0, stream>>>(lists, cursor, hist, compact, ccur);
    fixthresh_kernel<<<BATCH, HBINS, 0, stream>>>(meta, hist, compact, ccur);
    sortrank_kernel<<<BATCH, 1024, 0, stream>>>(compact, ccur, meta, winners);
    label_kernel<<<CHQ * BATCH, 256, 0, stream>>>(dis, winners, out);
}

// Round 8
// 149.466 us; speedup vs baseline: 1.1750x; 1.1750x over previous
//
#include <hip/hip_runtime.h>
#include <stdint.h>

#define BATCH 16
#define NPTS 500000
#define QPTS (NPTS / 4)        // 125000 quads
#define DBITS 21
#define DSIZE (1u << DBITS)
#define VOFF 969696            // di = vid + VOFF in [0, 2^21)
#define HBINS 256
#define CAP 8192
#define KTOP 512
#define NBKT 64
#define CPB 32768              // cells per bucket
#define CAPL 16384             // uint16 list capacity per bucket (2.1x mean 7812)
#define SCT 256                // scatter block threads
#define SCQ 512                // quads per scatter block (2048 points)
#define SCB ((QPTS + SCQ - 1) / SCQ)   // 245 blocks per batch
#define CHQ ((QPTS + 255) / 256)       // 489 label chunks per batch
#define CCAP 262144            // compact entries capacity per batch (~100k used)
#define WBITS 11
#define WSIZE (1 << WBITS)
#define WMASK (WSIZE - 1)
#define WEMPTY 0xFFFFFFFFu
#define M_ORIGIN 0
#define NZERO (BATCH * NBKT + BATCH + BATCH * HBINS + BATCH * 8)  // 5264 ints

typedef int ivec4 __attribute__((ext_vector_type(4)));

// Must match JAX/np exactly: IEEE f32 divide (NOT *5.0f), trunc-toward-zero cast.
__device__ __forceinline__ uint32_t didx_of(float x, float y, float z) {
    int vx = (int)(x / 0.2f);
    int vy = (int)(y / 0.2f);
    int vz = (int)(z / 0.2f);
    int di = vx * 10000 + vy * 100 + vz + VOFF;
    di = di < 0 ? 0 : di;
    di = di > (int)DSIZE - 1 ? (int)DSIZE - 1 : di;  // unreachable (9.6 sigma); safety only
    return (uint32_t)di;
}

// Plain (cacheable) loads: coords are 96 MB and fit L3; scatter+label both read them.
__device__ __forceinline__ void didx4_of(const float* base, int q, uint32_t di[4]) {
    const float4* cp = (const float4*)(base) + (size_t)q * 3;
    float4 f0 = cp[0], f1 = cp[1], f2 = cp[2];
    di[0] = didx_of(f0.x, f0.y, f0.z);
    di[1] = didx_of(f0.w, f1.x, f1.y);
    di[2] = didx_of(f1.z, f1.w, f2.x);
    di[3] = didx_of(f2.y, f2.z, f2.w);
}

__device__ __forceinline__ uint32_t bkt_of(uint32_t d) {
    return ((d >> 15) ^ (d >> 9)) & 63u;   // A ^ B: decorrelates Gaussian vx alignment
}

// Replaces hipMemsetAsync (each small fill cost ~55us in graph replay!).
__global__ void init_kernel(int* __restrict__ zero_base, unsigned int* __restrict__ winners) {
    int i = blockIdx.x * 256 + threadIdx.x;
    if (i < NZERO) zero_base[i] = 0;
    if (i < BATCH * WSIZE) winners[i] = WEMPTY;
}

// LDS-staged radix partition: bucket-sort 2048 points in LDS, then flush each
// bucket run COALESCED to its global list. 64 global atomics per block.
__global__ void __launch_bounds__(SCT) scatter_kernel(const float* __restrict__ coords,
                                                      uint16_t* __restrict__ lists,
                                                      int* __restrict__ cursor,
                                                      int* __restrict__ meta) {
    int id = blockIdx.x;
    int b = id & 15;
    int chunk = id >> 4;
    int t = threadIdx.x;
    __shared__ uint32_t ebuf[SCQ * 4];   // 8 KB, bucket-sorted entries
    __shared__ int bcount[NBKT], bstart[NBKT], brun[NBKT], gbase[NBKT], stot;
    if (t < NBKT) { bcount[t] = 0; brun[t] = 0; }
    __syncthreads();
    int q0 = chunk * SCQ + t;
    int q1 = q0 + SCT;
    const float* cb = coords + (size_t)b * NPTS * 3;
    uint32_t di[2][4];
    bool val[2] = {q0 < QPTS, q1 < QPTS};
#pragma unroll
    for (int p = 0; p < 2; ++p) {
        if (!val[p]) continue;
        didx4_of(cb, p ? q1 : q0, di[p]);
#pragma unroll
        for (int u = 0; u < 4; ++u) {
            uint32_t d = di[p][u];
            if (d == (uint32_t)VOFF)
                atomicAdd(&meta[b * 8 + M_ORIGIN], 1);  // rare (~254/batch)
            else
                atomicAdd(&bcount[bkt_of(d)], 1);
        }
    }
    __syncthreads();
    if (t < NBKT) {  // threads 0..63 = wave 0: shfl inclusive scan
        int c = bcount[t];
        int inc = c;
#pragma unroll
        for (int o = 1; o < NBKT; o <<= 1) {
            int v = __shfl_up(inc, o);
            if (t >= o) inc += v;
        }
        bstart[t] = inc - c;
        gbase[t] = atomicAdd(&cursor[b * NBKT + t], c);
        if (t == NBKT - 1) stot = inc;
    }
    __syncthreads();
#pragma unroll
    for (int p = 0; p < 2; ++p) {
        if (!val[p]) continue;
#pragma unroll
        for (int u = 0; u < 4; ++u) {
            uint32_t d = di[p][u];
            if (d == (uint32_t)VOFF) continue;
            uint32_t bk = bkt_of(d);
            int pos = bstart[bk] + atomicAdd(&brun[bk], 1);
            ebuf[pos] = (bk << 16) | (((d >> 15) << 9) | (d & 511u));
        }
    }
    __syncthreads();
    uint16_t* lb = lists + (size_t)b * NBKT * CAPL;
    int n = stot;
    for (int i = t; i < n; i += SCT) {  // adjacent i -> same bucket -> coalesced stores
        uint32_t w = ebuf[i];
        uint32_t bk = w >> 16;
        int gi = gbase[bk] + (i - bstart[bk]);
        if (gi < CAPL) lb[bk * CAPL + gi] = (uint16_t)(w & 0x7FFFu);
    }
}

// One block per (batch,bucket): LDS byte counts -> histogram + COMPACT nonzero cells
// as packed entries ((255-count)<<21 | di). No dense grid ever hits global memory.
__global__ void __launch_bounds__(256) count_kernel(const uint16_t* __restrict__ lists,
                                                    const int* __restrict__ cursor,
                                                    int* __restrict__ hist,
                                                    uint32_t* __restrict__ compact,
                                                    int* __restrict__ ccur) {
    __shared__ unsigned int cnt[CPB / 4];  // 32 KB
    __shared__ int lhist[HBINS];
    __shared__ int ltot, lrun, gbase;
    int id = blockIdx.x;
    int b = id & 15;
    uint32_t bkt = (uint32_t)(id >> 4);
    int t = threadIdx.x;
    for (int i = t; i < CPB / 4; i += 256) cnt[i] = 0;
    lhist[t] = 0;
    if (t == 0) { ltot = 0; lrun = 0; }
    __syncthreads();
    const uint16_t* list = lists + ((size_t)b * NBKT + bkt) * CAPL;
    int n = cursor[b * NBKT + bkt];
    if (n > CAPL) n = CAPL;
    for (int i = t; i < n; i += 256) {
        uint32_t e = list[i];  // (A<<9)|C
        atomicAdd(&cnt[e >> 2], 1u << ((e & 3u) * 8u));  // fire-and-forget LDS atomic
    }
    __syncthreads();
    // pass A: histogram + count my nonzero cells
    int mycnt = 0;
    for (int i = t; i < CPB / 4; i += 256) {
        unsigned int w = cnt[i];
        if (!w) continue;
#pragma unroll
        for (int j = 0; j < 4; ++j) {
            unsigned int c = (w >> (j * 8)) & 0xFFu;
            if (c) { atomicAdd(&lhist[c], 1); ++mycnt; }
        }
    }
    if (mycnt) atomicAdd(&ltot, mycnt);
    __syncthreads();
    if (t == 0) gbase = atomicAdd(&ccur[b], ltot);
    if (lhist[t]) atomicAdd(&hist[b * HBINS + t], lhist[t]);
    __syncthreads();
    // pass B: emit packed entries into reserved range
    uint32_t* cmp = compact + (size_t)b * CCAP;
    for (int i = t; i < CPB / 4; i += 256) {
        unsigned int w = cnt[i];
        if (!w) continue;
#pragma unroll
        for (int j = 0; j < 4; ++j) {
            unsigned int c = (w >> (j * 8)) & 0xFFu;
            if (c) {
                uint32_t local = (uint32_t)i * 4u + (uint32_t)j;
                uint32_t A = local >> 9, C = local & 511u, B = bkt ^ A;
                uint32_t di = (A << 15) | (B << 9) | C;
                int slot = atomicAdd(&lrun, 1);
                int idx = gbase + slot;
                if (idx < CCAP) cmp[idx] = ((255u - c) << DBITS) | di;
            }
        }
    }
}

// Fused: threshold scan (origin-adjusted) -> filter -> LDS bitonic sort -> winner hash.
__global__ void __launch_bounds__(1024) sortrank_kernel(const uint32_t* __restrict__ compact,
                                                        const int* __restrict__ ccur,
                                                        const int* __restrict__ hist,
                                                        const int* __restrict__ meta,
                                                        unsigned int* __restrict__ winners) {
    __shared__ uint32_t s[CAP];  // 32 KB
    __shared__ int ls[HBINS];
    __shared__ int sT, sScnt;
    int b = blockIdx.x;
    int t = threadIdx.x;
    int oc = meta[b * 8 + M_ORIGIN];
    int ocl = oc > 255 ? 255 : oc;  // origin is the unique top cell (~254 vs ~35); rank-safe
    if (t == 0) { sT = 1; sScnt = 0; }
    if (t < HBINS) ls[t] = (t >= 1 ? hist[b * HBINS + t] : 0) + ((oc > 0 && t == ocl) ? 1 : 0);
    __syncthreads();
    for (int off = 1; off < HBINS; off <<= 1) {  // suffix scan; ALL threads at barriers
        int v = 0;
        if (t < HBINS && t + off < HBINS) v = ls[t + off];
        __syncthreads();
        if (t < HBINS) ls[t] += v;
        __syncthreads();
    }
    int U = ls[1];
    int mode = (U > KTOP) ? 1 : 0;
    if (mode && t >= 1 && t < HBINS && ls[t] >= KTOP && (t == HBINS - 1 || ls[t + 1] < KTOP))
        sT = t;  // unique such t
    __syncthreads();
    uint32_t T = mode ? (uint32_t)sT : 1u;
    uint32_t maxtop = 255u - T;  // keep entries with count >= T
    int n = ccur[b];
    if (n > CCAP) n = CCAP;
    const uint32_t* cmp = compact + (size_t)b * CCAP;
    for (int i = t; i < n; i += 1024) {
        uint32_t e = cmp[i];
        if (!mode || (e >> DBITS) <= maxtop) {
            uint32_t key = mode ? e : (e & (DSIZE - 1u));  // mode0: rank by di only
            int idx = atomicAdd(&sScnt, 1);
            if (idx < CAP) s[idx] = key;
        }
    }
    if (t == 0 && oc > 0) {  // inject origin entry
        uint32_t c = (uint32_t)ocl;
        if (!mode || c >= T) {
            uint32_t key = mode ? (((255u - c) << DBITS) | (uint32_t)VOFF) : (uint32_t)VOFF;
            int idx = atomicAdd(&sScnt, 1);
            if (idx < CAP) s[idx] = key;
        }
    }
    __syncthreads();
    int nk = sScnt < CAP ? sScnt : CAP;
    int P = 2;
    while (P < nk) P <<= 1;
    for (int i = nk + t; i < P; i += 1024) s[i] = 0xFFFFFFFFu;  // real keys < 2^30
    __syncthreads();
    for (int k = 2; k <= P; k <<= 1) {
        for (int j = k >> 1; j > 0; j >>= 1) {
            for (int i = t; i < P; i += 1024) {
                int l = i ^ j;
                if (l > i) {
                    uint32_t a = s[i], c2 = s[l];
                    bool asc = ((i & k) == 0);
                    if ((asc && a > c2) || (!asc && a < c2)) { s[i] = c2; s[l] = a; }
                }
            }
            __syncthreads();
        }
    }
    int nsel = mode ? (nk < KTOP ? nk : KTOP) : nk;  // mode0: nk = U <= 512
    unsigned int* wb = winners + (size_t)b * WSIZE;
    for (int j = t; j < nsel; j += 1024) {
        uint32_t di = s[j] & (DSIZE - 1u);
        uint32_t ins = (di << 9) | (uint32_t)j;  // 30 bits, != WEMPTY
        uint32_t h = (di * 0x9E3779B1u) >> (32 - WBITS);
        while (atomicCAS(&wb[h], WEMPTY, ins) != WEMPTY) h = (h + 1) & WMASK;
    }
}

// Recompute didx per point (coords L3-hot); probe 8 KB winner hash; -1 on first empty.
__global__ void label_kernel(const float* __restrict__ coords,
                             const unsigned int* __restrict__ winners,
                             int* __restrict__ out) {
    int id = blockIdx.x;
    int b = id & 15;
    int q = (id >> 4) * 256 + threadIdx.x;
    if (q >= QPTS) return;
    uint32_t di[4];
    didx4_of(coords + (size_t)b * NPTS * 3, q, di);
    const unsigned int* wb = winners + (size_t)b * WSIZE;
    int r[4];
#pragma unroll
    for (int u = 0; u < 4; ++u) {
        uint32_t h = (di[u] * 0x9E3779B1u) >> (32 - WBITS);
        int rr = -1;
        while (true) {
            unsigned int w = wb[h];
            if (w == WEMPTY) break;
            if ((w >> 9) == di[u]) { rr = (int)(w & 0x1FFu); break; }
            h = (h + 1) & WMASK;
        }
        r[u] = rr;
    }
    ivec4 r4 = {r[0], r[1], r[2], r[3]};
    __builtin_nontemporal_store(r4, (ivec4*)(out + (size_t)b * NPTS + (size_t)q * 4));
}

extern "C" void kernel_launch(void* const* d_in, const int* in_sizes, int n_in,
                              void* d_out, int out_size, void* d_ws, size_t ws_size,
                              hipStream_t stream) {
    const float* coords = (const float*)d_in[0];
    int* out = (int*)d_out;
    char* ws = (char*)d_ws;

    size_t off = 0;
    uint16_t* lists = (uint16_t*)(ws + off);           off += (size_t)BATCH * NBKT * CAPL * 2;  // 32 MB
    uint32_t* compact = (uint32_t*)(ws + off);         off += (size_t)BATCH * CCAP * 4;         // 16 MB
    int* cursor = (int*)(ws + off);                    off += (size_t)BATCH * NBKT * 4;         // 4 KB
    int* ccur = (int*)(ws + off);                      off += (size_t)BATCH * 4;                // 64 B
    int* hist = (int*)(ws + off);                      off += (size_t)BATCH * HBINS * 4;        // 16 KB
    int* meta = (int*)(ws + off);                      off += (size_t)BATCH * 8 * 4;            // 512 B
    unsigned int* winners = (unsigned int*)(ws + off); off += (size_t)BATCH * WSIZE * 4;        // 128 KB

    // NO hipMemsetAsync: small fills cost ~55us each in graph replay (R7 profile).
    // cursor..meta are contiguous ints (NZERO total); winners filled 0xFF.
    init_kernel<<<(BATCH * WSIZE + 255) / 256, 256, 0, stream>>>(cursor, winners);

    scatter_kernel<<<SCB * BATCH, SCT, 0, stream>>>(coords, lists, cursor, meta);
    count_kernel<<<NBKT * BATCH, 256, 0, stream>>>(lists, cursor, hist, compact, ccur);
    sortrank_kernel<<<BATCH, 1024, 0, stream>>>(compact, ccur, hist, meta, winners);
    label_kernel<<<CHQ * BATCH, 256, 0, stream>>>(coords, winners, out);
}